// Round 1
// baseline (435.528 us; speedup 1.0000x reference)
//
#include <hip/hip_runtime.h>
#include <hip/hip_bf16.h>
#include <math.h>

// Suffix-max scan along H (reverse), NCHW layout: x[8,128,256,256] f32.
// out[n,c,h,w] = max over j>=h of x[n,c,j,w].
//
// One block per (n,c) slab; 256 threads, thread t owns column w=t.
// Serial scan h=255..0 with a running max; loads are coalesced 256B/wave,
// independent across h (unrolled for MLP-level pipelining).

#define H 256
#define W 256

__global__ __launch_bounds__(256) void VerticalLinePool_kernel(
    const float* __restrict__ x, float* __restrict__ out) {
    const int w = threadIdx.x;                       // 0..255
    const size_t base = (size_t)blockIdx.x * (H * W) + w;
    const float* __restrict__ xp = x + base;
    float* __restrict__ op = out + base;

    float acc = -INFINITY;
#pragma unroll 8
    for (int h = H - 1; h >= 0; --h) {
        float v = xp[(size_t)h * W];
        acc = fmaxf(acc, v);
        op[(size_t)h * W] = acc;
    }
}

extern "C" void kernel_launch(void* const* d_in, const int* in_sizes, int n_in,
                              void* d_out, int out_size, void* d_ws, size_t ws_size,
                              hipStream_t stream) {
    const float* x = (const float*)d_in[0];
    float* out = (float*)d_out;
    const int slabs = in_sizes[0] / (H * W);        // 8*128 = 1024
    VerticalLinePool_kernel<<<slabs, 256, 0, stream>>>(x, out);
}

// Round 3
// 432.378 us; speedup vs baseline: 1.0073x; 1.0073x over previous
//
#include <hip/hip_runtime.h>
#include <hip/hip_bf16.h>
#include <math.h>

// Suffix-max scan along H (reverse), NCHW: x[8,128,256,256] f32.
// out[n,c,h,w] = max_{j>=h} x[n,c,j,w].
//
// R1 theory: R0 (thread-per-column scalar) made ~8K concurrent 256B-granular
// 1KiB-strided streams -> HBM row-buffer thrash -> 1.2 TB/s effective.
// Fix: thread owns 4 columns (16B vector); a wave's 64 lanes cover the full
// W=256 row (1 KiB). Wave walks h descending => one linear (reversed)
// 256 KiB stream per wave. 4 waves/block, one slab per wave, 256 blocks.
// unroll 16 => ~16 KiB reads in flight per wave; nontemporal (touch-once).
//
// R2 fix: nontemporal builtins need a NATIVE clang vector type, not
// HIP_vector_type<float,4> -> use ext_vector_type(4).

#define H 256
#define W 256

typedef float f32x4 __attribute__((ext_vector_type(4)));

__global__ __launch_bounds__(256) void VerticalLinePool_kernel(
    const float* __restrict__ x, float* __restrict__ out) {
    const int lane = threadIdx.x & 63;              // 0..63 -> f32x4 index in row
    const int wv   = threadIdx.x >> 6;              // 0..3  -> slab within block
    const int slab = blockIdx.x * 4 + wv;           // 0..1023 (n,c)

    const size_t base = (size_t)slab * (H * W) + (size_t)lane * 4;
    const f32x4* __restrict__ xp = (const f32x4*)(x + base);
    f32x4* __restrict__ op = (f32x4*)(out + base);
    // row stride in f32x4 units: W/4 = 64

    f32x4 acc = (f32x4)(-INFINITY);

#pragma unroll 16
    for (int h = H - 1; h >= 0; --h) {
        f32x4 v = __builtin_nontemporal_load(&xp[(size_t)h * (W / 4)]);
        acc.x = fmaxf(acc.x, v.x);
        acc.y = fmaxf(acc.y, v.y);
        acc.z = fmaxf(acc.z, v.z);
        acc.w = fmaxf(acc.w, v.w);
        __builtin_nontemporal_store(acc, &op[(size_t)h * (W / 4)]);
    }
}

extern "C" void kernel_launch(void* const* d_in, const int* in_sizes, int n_in,
                              void* d_out, int out_size, void* d_ws, size_t ws_size,
                              hipStream_t stream) {
    const float* x = (const float*)d_in[0];
    float* out = (float*)d_out;
    const int slabs = in_sizes[0] / (H * W);        // 8*128 = 1024
    VerticalLinePool_kernel<<<slabs / 4, 256, 0, stream>>>(x, out);
}

// Round 4
// 423.942 us; speedup vs baseline: 1.0273x; 1.0199x over previous
//
#include <hip/hip_runtime.h>
#include <hip/hip_bf16.h>
#include <math.h>

// Suffix-max scan along H (reverse), NCHW: x[8,128,256,256] f32.
// out[n,c,h,w] = max_{j>=h} x[n,c,j,w].
//
// R4 theory: R0/R3's identical perf (~433us) despite opposite access
// patterns => the limiter is the per-iteration load->fmax->store chain:
// in-order vmcnt retirement couples each load's waitcnt to the previous
// store's completion, serializing the h-loop on round-trip latency.
//
// Fix: register-resident chunked scan. Block = 256 threads = (4 chunks x
// 64 columns). Phase 1 (pure loads): thread suffix-scans its 64-row chunk
// into 64 VGPRs -- 64 independent loads, no stores in the vmcnt queue.
// LDS-share the 4 chunk totals per column, one barrier. Phase 2 (pure
// stores): out[h] = max(s_local[h], max of chunk totals above). Traffic
// stays optimal: 256 MiB read + 256 MiB write, touch-once.

#define H 256
#define W 256
#define CH 64  // chunk height (H / 4)

typedef float f32;

__global__ __launch_bounds__(256) void VerticalLinePool_kernel(
    const float* __restrict__ x, float* __restrict__ out) {
    const int tid = threadIdx.x;
    const int c  = tid >> 6;             // chunk index 0..3 (wave-uniform)
    const int wl = tid & 63;             // lane -> column within quarter
    const int q    = blockIdx.x & 3;     // w-quarter 0..3
    const int slab = blockIdx.x >> 2;    // (n,c) slab 0..1023

    const size_t col = (size_t)slab * (H * W) + (size_t)q * 64 + wl;
    const float* __restrict__ xp = x + col;
    float* __restrict__ op = out + col;

    const int h0 = c * CH;

    // Phase 1: pure-load suffix scan of this chunk, kept in registers.
    float s[CH];
    float run = -INFINITY;
#pragma unroll
    for (int i = CH - 1; i >= 0; --i) {
        float v = __builtin_nontemporal_load(&xp[(size_t)(h0 + i) * W]);
        run = fmaxf(run, v);
        s[i] = run;
    }

    // Share chunk totals; chunk c needs max over chunks c+1..3.
    __shared__ float tot[4][64];
    tot[c][wl] = run;
    __syncthreads();

    float M = -INFINITY;                 // branches are wave-uniform (c = wave id)
    if (c < 3) M = tot[c + 1][wl];
    if (c < 2) M = fmaxf(M, tot[c + 2][wl]);
    if (c < 1) M = fmaxf(M, tot[c + 3][wl]);

    // Phase 2: pure-store pass.
#pragma unroll
    for (int i = 0; i < CH; ++i) {
        __builtin_nontemporal_store(fmaxf(s[i], M), &op[(size_t)(h0 + i) * W]);
    }
}

extern "C" void kernel_launch(void* const* d_in, const int* in_sizes, int n_in,
                              void* d_out, int out_size, void* d_ws, size_t ws_size,
                              hipStream_t stream) {
    const float* x = (const float*)d_in[0];
    float* out = (float*)d_out;
    const int slabs = in_sizes[0] / (H * W);   // 8*128 = 1024
    VerticalLinePool_kernel<<<slabs * 4, 256, 0, stream>>>(x, out);
}